// Round 1
// baseline (173.869 us; speedup 1.0000x reference)
//
#include <hip/hip_runtime.h>
#include <math.h>

// out = sum_j W[j] * (sum_n |yt[n,j]-yp[n,j]|) / (sum_n yt[n,j])
// (outer mean's 1/N cancels the 1/N inside col_mean)
//
// R8 = re-run of R7 (infra failure: container died twice, no data).
// R7 = R6 probe with compile fix: __builtin_nontemporal_load requires a
// native vector type, not HIP_vector_type. Use ext_vector_type(4).
//
// R1-R5 established: five different access mechanisms (uncoalesced VGPR,
// coalesced VGPR, batched, sched_barrier, global_load_lds DMA with 8 KB/wave
// in flight) ALL pin at 63-67 us = 2.58 TB/s read, FETCH 82 MB + ~84 MB LLC
// = exactly the input, VALU ~3%. Theory: per-CU outstanding-miss-line cap
// (TCP/MSHR) x LLC/HBM latency caps CU-issued read-only streaming at
// ~2.6 TB/s. nt (no-allocate) is the last cache-path knob: streaming data,
// zero reuse, L2 allocation is pure overhead. If neutral -> roofline.
//
// Column math (R2): float4 q = tid + k*TTH, component c -> col (4q+c)%5;
// 4*TTH mod 5 == 2 -> col = (c + 2k + 4*tid)%5. (c+2k)%5 static after
// unroll; per-thread rotation un-done once at the end.

#define GRID 2048
#define BLOCK 256
#define TTH (GRID * BLOCK)  // 524288; 4*TTH mod 5 == 2
#define KLOADS 10           // 524288*10 = 5242880 float4s per array, exact

typedef float vf4 __attribute__((ext_vector_type(4)));

__global__ __launch_bounds__(BLOCK) void regress_reduce_fast(
    const vf4* __restrict__ yt4, const vf4* __restrict__ yp4,
    float* __restrict__ partials) {
  const int tid = blockIdx.x * BLOCK + threadIdx.x;

  // rotated-space accumulators: local m corresponds to column (m + 4*tid)%5
  float s[5] = {0.f, 0.f, 0.f, 0.f, 0.f};
  float a[5] = {0.f, 0.f, 0.f, 0.f, 0.f};

#pragma unroll
  for (int k = 0; k < KLOADS; ++k) {
    const vf4 tv = __builtin_nontemporal_load(yt4 + tid + (long long)k * TTH);
    const vf4 pv = __builtin_nontemporal_load(yp4 + tid + (long long)k * TTH);
    const int m0 = (2 * k + 0) % 5;  // static after unroll
    const int m1 = (2 * k + 1) % 5;
    const int m2 = (2 * k + 2) % 5;
    const int m3 = (2 * k + 3) % 5;
    s[m0] += tv.x; a[m0] += fabsf(tv.x - pv.x);
    s[m1] += tv.y; a[m1] += fabsf(tv.y - pv.y);
    s[m2] += tv.z; a[m2] += fabsf(tv.z - pv.z);
    s[m3] += tv.w; a[m3] += fabsf(tv.w - pv.w);
  }

  // un-rotate into global column space + block reduction via LDS
  __shared__ float red[BLOCK][11];  // +1 pad
  const int tix = threadIdx.x;
  const int rr = tid % 5;
#pragma unroll
  for (int m = 0; m < 5; ++m) {
    int g = m - rr; if (g < 0) g += 5;
    red[tix][g] = s[m];
    red[tix][5 + g] = a[m];
  }
  __syncthreads();
#pragma unroll
  for (int off = BLOCK / 2; off > 0; off >>= 1) {
    if (tix < off) {
#pragma unroll
      for (int v = 0; v < 10; ++v) red[tix][v] += red[tix + off][v];
    }
    __syncthreads();
  }
  if (tix < 10) partials[blockIdx.x * 10 + tix] = red[0][tix];  // deterministic
}

// generic fallback (any nrows), correctness-first
__global__ __launch_bounds__(BLOCK) void regress_reduce_generic(
    const float* __restrict__ yt, const float* __restrict__ yp,
    float* __restrict__ partials, long long nrows) {
  float s[5] = {0.f, 0.f, 0.f, 0.f, 0.f};
  float a[5] = {0.f, 0.f, 0.f, 0.f, 0.f};
  const long long tid = (long long)blockIdx.x * blockDim.x + threadIdx.x;
  const long long stride = (long long)gridDim.x * blockDim.x;
  for (long long r = tid; r < nrows; r += stride) {
#pragma unroll
    for (int c = 0; c < 5; ++c) {
      float tv = yt[r * 5 + c];
      s[c] += tv;
      a[c] += fabsf(tv - yp[r * 5 + c]);
    }
  }
  __shared__ float red[BLOCK][11];
  const int t = threadIdx.x;
#pragma unroll
  for (int c = 0; c < 5; ++c) { red[t][c] = s[c]; red[t][5 + c] = a[c]; }
  __syncthreads();
#pragma unroll
  for (int off = BLOCK / 2; off > 0; off >>= 1) {
    if (t < off) {
#pragma unroll
      for (int v = 0; v < 10; ++v) red[t][v] += red[t + off][v];
    }
    __syncthreads();
  }
  if (t < 10) partials[blockIdx.x * 10 + t] = red[0][t];
}

__global__ __launch_bounds__(256) void regress_finalize(
    const float* __restrict__ partials, int nblocks, float* __restrict__ out) {
  float acc[10] = {0.f, 0.f, 0.f, 0.f, 0.f, 0.f, 0.f, 0.f, 0.f, 0.f};
  for (int b = threadIdx.x; b < nblocks; b += 256) {
#pragma unroll
    for (int v = 0; v < 10; ++v) acc[v] += partials[b * 10 + v];
  }
#pragma unroll
  for (int off = 32; off > 0; off >>= 1) {
#pragma unroll
    for (int v = 0; v < 10; ++v) acc[v] += __shfl_down(acc[v], off, 64);
  }
  __shared__ float lds[4][10];
  const int lane = threadIdx.x & 63;
  const int wave = threadIdx.x >> 6;
  if (lane == 0) {
#pragma unroll
    for (int v = 0; v < 10; ++v) lds[wave][v] = acc[v];
  }
  __syncthreads();
  if (threadIdx.x == 0) {
    const float W[5] = {0.3f, 0.175f, 0.175f, 0.175f, 0.175f};
    float r = 0.f;
#pragma unroll
    for (int c = 0; c < 5; ++c) {
      float sc = lds[0][c] + lds[1][c] + lds[2][c] + lds[3][c];
      float ac = lds[0][5 + c] + lds[1][5 + c] + lds[2][5 + c] + lds[3][5 + c];
      r += W[c] * ac / sc;
    }
    *out = r;
  }
}

extern "C" void kernel_launch(void* const* d_in, const int* in_sizes, int n_in,
                              void* d_out, int out_size, void* d_ws, size_t ws_size,
                              hipStream_t stream) {
  const float* yt = (const float*)d_in[0];
  const float* yp = (const float*)d_in[1];
  const long long nelem = (long long)in_sizes[0];
  const long long nrows = nelem / 5;
  float* partials = (float*)d_ws;  // GRID * 10 floats = 80 KB

  if (nelem == (long long)TTH * KLOADS * 4) {
    regress_reduce_fast<<<GRID, BLOCK, 0, stream>>>(
        (const vf4*)yt, (const vf4*)yp, partials);
  } else {
    regress_reduce_generic<<<GRID, BLOCK, 0, stream>>>(yt, yp, partials, nrows);
  }
  regress_finalize<<<1, 256, 0, stream>>>(partials, GRID, (float*)d_out);
}

// Round 2
// 169.450 us; speedup vs baseline: 1.0261x; 1.0261x over previous
//
#include <hip/hip_runtime.h>
#include <math.h>

// out = sum_j W[j] * (sum_n |yt[n,j]-yp[n,j]|) / (sum_n yt[n,j])
// (outer mean's 1/N cancels the 1/N inside col_mean)
//
// R9 = occupancy probe. R8 (nontemporal loads) displaced the kernel from the
// rocprof top-5 (fills at 49.6-51.2 us now dominate) => reduce_fast < 49.6 us,
// >= 3.4 TB/s read, up from the 2.58 TB/s cap of R1-R5. nt helped: poison-fill
// leaves inputs ~L3-resident; nt skips L2 allocation and rides L3-hit latency.
// Remaining theory: latency x outstanding bound. 20 clustered float4 loads
// => ~100+ VGPR => <=16 waves/CU. Cap VGPR at 64 via __launch_bounds__(256,8):
// 2048 blocks = 8 blocks/CU = 32 waves/CU (8/SIMD), exactly filling the
// 512-reg file. If wave-count-limited: ~36-42 us. If per-CU MSHR cap: neutral
// -> roofline declared next round (all axes exhausted).
//
// Column math (R2): float4 q = tid + k*TTH, component c -> col (4q+c)%5;
// 4*TTH mod 5 == 2 -> col = (c + 2k + 4*tid)%5. (c+2k)%5 static after
// unroll; per-thread rotation un-done once at the end.

#define GRID 2048
#define BLOCK 256
#define TTH (GRID * BLOCK)  // 524288; 4*TTH mod 5 == 2
#define KLOADS 10           // 524288*10 = 5242880 float4s per array, exact

typedef float vf4 __attribute__((ext_vector_type(4)));

__global__ __launch_bounds__(BLOCK, 8) void regress_reduce_fast(
    const vf4* __restrict__ yt4, const vf4* __restrict__ yp4,
    float* __restrict__ partials) {
  const int tid = blockIdx.x * BLOCK + threadIdx.x;

  // rotated-space accumulators: local m corresponds to column (m + 4*tid)%5
  float s[5] = {0.f, 0.f, 0.f, 0.f, 0.f};
  float a[5] = {0.f, 0.f, 0.f, 0.f, 0.f};

#pragma unroll
  for (int k = 0; k < KLOADS; ++k) {
    const vf4 tv = __builtin_nontemporal_load(yt4 + tid + (long long)k * TTH);
    const vf4 pv = __builtin_nontemporal_load(yp4 + tid + (long long)k * TTH);
    const int m0 = (2 * k + 0) % 5;  // static after unroll
    const int m1 = (2 * k + 1) % 5;
    const int m2 = (2 * k + 2) % 5;
    const int m3 = (2 * k + 3) % 5;
    s[m0] += tv.x; a[m0] += fabsf(tv.x - pv.x);
    s[m1] += tv.y; a[m1] += fabsf(tv.y - pv.y);
    s[m2] += tv.z; a[m2] += fabsf(tv.z - pv.z);
    s[m3] += tv.w; a[m3] += fabsf(tv.w - pv.w);
  }

  // un-rotate into global column space + block reduction via LDS
  __shared__ float red[BLOCK][11];  // +1 pad
  const int tix = threadIdx.x;
  const int rr = tid % 5;
#pragma unroll
  for (int m = 0; m < 5; ++m) {
    int g = m - rr; if (g < 0) g += 5;
    red[tix][g] = s[m];
    red[tix][5 + g] = a[m];
  }
  __syncthreads();
#pragma unroll
  for (int off = BLOCK / 2; off > 0; off >>= 1) {
    if (tix < off) {
#pragma unroll
      for (int v = 0; v < 10; ++v) red[tix][v] += red[tix + off][v];
    }
    __syncthreads();
  }
  if (tix < 10) partials[blockIdx.x * 10 + tix] = red[0][tix];  // deterministic
}

// generic fallback (any nrows), correctness-first
__global__ __launch_bounds__(BLOCK) void regress_reduce_generic(
    const float* __restrict__ yt, const float* __restrict__ yp,
    float* __restrict__ partials, long long nrows) {
  float s[5] = {0.f, 0.f, 0.f, 0.f, 0.f};
  float a[5] = {0.f, 0.f, 0.f, 0.f, 0.f};
  const long long tid = (long long)blockIdx.x * blockDim.x + threadIdx.x;
  const long long stride = (long long)gridDim.x * blockDim.x;
  for (long long r = tid; r < nrows; r += stride) {
#pragma unroll
    for (int c = 0; c < 5; ++c) {
      float tv = yt[r * 5 + c];
      s[c] += tv;
      a[c] += fabsf(tv - yp[r * 5 + c]);
    }
  }
  __shared__ float red[BLOCK][11];
  const int t = threadIdx.x;
#pragma unroll
  for (int c = 0; c < 5; ++c) { red[t][c] = s[c]; red[t][5 + c] = a[c]; }
  __syncthreads();
#pragma unroll
  for (int off = BLOCK / 2; off > 0; off >>= 1) {
    if (t < off) {
#pragma unroll
      for (int v = 0; v < 10; ++v) red[t][v] += red[t + off][v];
    }
    __syncthreads();
  }
  if (t < 10) partials[blockIdx.x * 10 + t] = red[0][t];
}

__global__ __launch_bounds__(256) void regress_finalize(
    const float* __restrict__ partials, int nblocks, float* __restrict__ out) {
  float acc[10] = {0.f, 0.f, 0.f, 0.f, 0.f, 0.f, 0.f, 0.f, 0.f, 0.f};
  for (int b = threadIdx.x; b < nblocks; b += 256) {
#pragma unroll
    for (int v = 0; v < 10; ++v) acc[v] += partials[b * 10 + v];
  }
#pragma unroll
  for (int off = 32; off > 0; off >>= 1) {
#pragma unroll
    for (int v = 0; v < 10; ++v) acc[v] += __shfl_down(acc[v], off, 64);
  }
  __shared__ float lds[4][10];
  const int lane = threadIdx.x & 63;
  const int wave = threadIdx.x >> 6;
  if (lane == 0) {
#pragma unroll
    for (int v = 0; v < 10; ++v) lds[wave][v] = acc[v];
  }
  __syncthreads();
  if (threadIdx.x == 0) {
    const float W[5] = {0.3f, 0.175f, 0.175f, 0.175f, 0.175f};
    float r = 0.f;
#pragma unroll
    for (int c = 0; c < 5; ++c) {
      float sc = lds[0][c] + lds[1][c] + lds[2][c] + lds[3][c];
      float ac = lds[0][5 + c] + lds[1][5 + c] + lds[2][5 + c] + lds[3][5 + c];
      r += W[c] * ac / sc;
    }
    *out = r;
  }
}

extern "C" void kernel_launch(void* const* d_in, const int* in_sizes, int n_in,
                              void* d_out, int out_size, void* d_ws, size_t ws_size,
                              hipStream_t stream) {
  const float* yt = (const float*)d_in[0];
  const float* yp = (const float*)d_in[1];
  const long long nelem = (long long)in_sizes[0];
  const long long nrows = nelem / 5;
  float* partials = (float*)d_ws;  // GRID * 10 floats = 80 KB

  if (nelem == (long long)TTH * KLOADS * 4) {
    regress_reduce_fast<<<GRID, BLOCK, 0, stream>>>(
        (const vf4*)yt, (const vf4*)yp, partials);
  } else {
    regress_reduce_generic<<<GRID, BLOCK, 0, stream>>>(yt, yp, partials, nrows);
  }
  regress_finalize<<<1, 256, 0, stream>>>(partials, GRID, (float*)d_out);
}